// Round 4
// baseline (340.266 us; speedup 1.0000x reference)
//
#include <hip/hip_runtime.h>
#include <hip/hip_fp16.h>

#define B_ 64
#define L_ 512
#define T_ 128
#define NTHR 64     // ONE wave per batch: no barriers anywhere

typedef _Float16 h2v __attribute__((ext_vector_type(2)));
typedef __fp16   h2b __attribute__((ext_vector_type(2)));   // builtin return type

__device__ __forceinline__ float dot2_acc(unsigned int e, unsigned int a, float c) {
#if __has_builtin(__builtin_amdgcn_fdot2)
    h2v ev = __builtin_bit_cast(h2v, e);
    h2v av = __builtin_bit_cast(h2v, a);
    return __builtin_amdgcn_fdot2(ev, av, c, false);
#else
    __half2 eh = __builtin_bit_cast(__half2, e);
    __half2 ah = __builtin_bit_cast(__half2, a);
    float2 ef = __half22float2(eh), af = __half22float2(ah);
    return c + ef.x * af.x + ef.y * af.y;
#endif
}

__device__ __forceinline__ unsigned int pack2(float a, float b) {
#if __has_builtin(__builtin_amdgcn_cvt_pkrtz)
    h2b h = __builtin_amdgcn_cvt_pkrtz(a, b);
    return __builtin_bit_cast(unsigned int, h);
#else
    __half2 h = __floats2half2_rn(a, b);
    return __builtin_bit_cast(unsigned int, h);
#endif
}

__global__ __launch_bounds__(NTHR, 1) void crf_nll_kernel(
        const float* __restrict__ feats,   // [B, L, T]
        const float* __restrict__ trans,   // [T, T]
        const int*   __restrict__ tags,    // [B, L]
        const int*   __restrict__ mask,    // [B, L]
        float*       __restrict__ out)     // [B]
{
    __shared__ __align__(16) unsigned int apk[2][T_ / 2];  // x as f16x2 over i-pairs

    const int lane = threadIdx.x;          // 0..63
    const int b    = blockIdx.x;

    const float*  featb  = feats + (size_t)b * L_ * T_;
    const float2* featb2 = (const float2*)featb;           // [L][64] pairs
    const float2* trans2 = (const float2*)trans;           // [T][64] pairs
    const int*    maskb  = mask + b * L_;
    const int*    tagb   = tags + b * L_;

    // ---- E columns (j0=2*lane, j1=2*lane+1) in registers, packed by i-pairs ----
    // EC0[w] = (E[2w][j0], E[2w+1][j0]) ; EC1[w] = same for j1
    unsigned int EC0[T_ / 2], EC1[T_ / 2];
    #pragma unroll
    for (int w = 0; w < T_ / 2; ++w) {
        float2 r0 = trans2[(2 * w) * (T_ / 2) + lane];      // E-row 2w,   cols j0,j1
        float2 r1 = trans2[(2 * w + 1) * (T_ / 2) + lane];  // E-row 2w+1, cols j0,j1
        EC0[w] = pack2(__expf(r0.x), __expf(r1.x));
        EC1[w] = pack2(__expf(r0.y), __expf(r1.y));
    }

    // ---- init: alpha_0 = emit_0 ----
    float2 e0 = featb2[lane];
    float m = fmaxf(e0.x, e0.y);
    #pragma unroll
    for (int off = 32; off >= 1; off >>= 1) m = fmaxf(m, __shfl_xor(m, off));
    float xc0 = __expf(e0.x - m);
    float xc1 = __expf(e0.y - m);
    float N = m;                          // running log-normalizer
    float S = xc0 + xc1;                  // exact sum of current x vector
    #pragma unroll
    for (int off = 32; off >= 1; off >>= 1) S += __shfl_xor(S, off);
    apk[0][lane] = pack2(xc0, xc1);       // same wave: in-order DS queue, no barrier

    // ---- emit/mask prefetch pipeline (depth 3) ----
    float2 fq  = featb2[1 * (T_ / 2) + lane];
    float2 fb1 = featb2[2 * (T_ / 2) + lane];
    float2 fb2 = featb2[3 * (T_ / 2) + lane];
    float exq0 = __expf(fq.x), exq1 = __expf(fq.y);
    int mkq = maskb[1], mkb1 = maskb[2], mkb2 = maskb[3];

    const float LOG128 = 4.8520302639196171f;
    int pr = 0;

    // ---- forward scan: barrier-free ----
    for (int t = 1; t < L_; ++t) {
        // prefetch emit/mask for t+3 (clamped) — latency hidden under dots
        const int tn = (t + 3 < L_) ? (t + 3) : (L_ - 1);
        float2 fn = featb2[tn * (T_ / 2) + lane];
        int    mn = maskb[tn];

        const float rcpC = 1.0f / (S * 128.0f);
        const float logC = __logf(S) + LOG128;

        float a00 = 0.f, a01 = 0.f, a02 = 0.f, a03 = 0.f;   // j0 chains
        float a10 = 0.f, a11 = 0.f, a12 = 0.f, a13 = 0.f;   // j1 chains
        const uint4* ap = (const uint4*)apk[pr];
        #pragma unroll
        for (int k = 0; k < 16; ++k) {
            uint4 a4 = ap[k];                               // broadcast ds_read_b128
            a00 = dot2_acc(EC0[4 * k + 0], a4.x, a00);
            a10 = dot2_acc(EC1[4 * k + 0], a4.x, a10);
            a01 = dot2_acc(EC0[4 * k + 1], a4.y, a01);
            a11 = dot2_acc(EC1[4 * k + 1], a4.y, a11);
            a02 = dot2_acc(EC0[4 * k + 2], a4.z, a02);
            a12 = dot2_acc(EC1[4 * k + 2], a4.z, a12);
            a03 = dot2_acc(EC0[4 * k + 3], a4.w, a03);
            a13 = dot2_acc(EC1[4 * k + 3], a4.w, a13);
        }
        const float ssum0 = (a00 + a01) + (a02 + a03);
        const float ssum1 = (a10 + a11) + (a12 + a13);

        const float x0 = ssum0 * exq0 * rcpC;
        const float x1 = ssum1 * exq1 * rcpC;
        if (mkq) { xc0 = x0; xc1 = x1; N += logC; }

        apk[pr ^ 1][lane] = pack2(xc0, xc1);

        // exact sum of committed vector (consumed next iter -> off critical path)
        float s = xc0 + xc1;
        #pragma unroll
        for (int off = 32; off >= 1; off >>= 1) s += __shfl_xor(s, off);
        S = s;

        // rotate prefetch pipeline
        exq0 = __expf(fb1.x); exq1 = __expf(fb1.y);
        mkq = mkb1;
        fb1 = fb2; mkb1 = mkb2;
        fb2 = fn;  mkb2 = mn;

        pr ^= 1;
    }

    // ---- norm = N + log(sum of final x) ----
    const float norm = N + __logf(S);

    // ---- gold path score ----
    float g = 0.f;
    for (int t = lane; t < L_; t += NTHR) {
        int tg = tagb[t];
        g += featb[t * T_ + tg] * (float)maskb[t];
        if (t + 1 < L_) {
            g += trans[tg * T_ + tagb[t + 1]] * (float)maskb[t + 1];
        }
    }
    #pragma unroll
    for (int off = 32; off >= 1; off >>= 1) g += __shfl_xor(g, off);

    if (lane == 0) out[b] = norm - g;
}

extern "C" void kernel_launch(void* const* d_in, const int* in_sizes, int n_in,
                              void* d_out, int out_size, void* d_ws, size_t ws_size,
                              hipStream_t stream) {
    const float* feats = (const float*)d_in[0];
    const float* trans = (const float*)d_in[1];
    const int*   tags  = (const int*)d_in[2];
    const int*   mask  = (const int*)d_in[3];
    float* out = (float*)d_out;

    crf_nll_kernel<<<B_, NTHR, 0, stream>>>(feats, trans, tags, mask, out);
}

// Round 5
// 321.238 us; speedup vs baseline: 1.0592x; 1.0592x over previous
//
#include <hip/hip_runtime.h>
#include <hip/hip_fp16.h>

#define B_ 64
#define L_ 512
#define T_ 128
#define NTHR 64     // ONE wave per batch: no barriers anywhere

typedef _Float16 h2v __attribute__((ext_vector_type(2)));
typedef __fp16   h2b __attribute__((ext_vector_type(2)));   // builtin return type

__device__ __forceinline__ float dot2_acc(unsigned int e, unsigned int a, float c) {
#if __has_builtin(__builtin_amdgcn_fdot2)
    h2v ev = __builtin_bit_cast(h2v, e);
    h2v av = __builtin_bit_cast(h2v, a);
    return __builtin_amdgcn_fdot2(ev, av, c, false);
#else
    __half2 eh = __builtin_bit_cast(__half2, e);
    __half2 ah = __builtin_bit_cast(__half2, a);
    float2 ef = __half22float2(eh), af = __half22float2(ah);
    return c + ef.x * af.x + ef.y * af.y;
#endif
}

__device__ __forceinline__ unsigned int pack2(float a, float b) {
#if __has_builtin(__builtin_amdgcn_cvt_pkrtz)
    h2b h = __builtin_amdgcn_cvt_pkrtz(a, b);
    return __builtin_bit_cast(unsigned int, h);
#else
    __half2 h = __floats2half2_rn(a, b);
    return __builtin_bit_cast(unsigned int, h);
#endif
}

__global__ __launch_bounds__(NTHR, 1) void crf_nll_kernel(
        const float* __restrict__ feats,   // [B, L, T]
        const float* __restrict__ trans,   // [T, T]
        const int*   __restrict__ tags,    // [B, L]
        const int*   __restrict__ mask,    // [B, L]
        float*       __restrict__ out)     // [B]
{
    __shared__ __align__(16) unsigned int apk[2][T_ / 2];  // x as f16x2 over i-pairs

    const int lane = threadIdx.x;          // 0..63
    const int b    = blockIdx.x;

    const float*  featb  = feats + (size_t)b * L_ * T_;
    const float2* featb2 = (const float2*)featb;           // [L][64] pairs
    const float2* trans2 = (const float2*)trans;           // [T][64] pairs
    const int*    maskb  = mask + b * L_;
    const int*    tagb   = tags + b * L_;

    // ---- E columns (j0=2*lane, j1=2*lane+1) in registers, packed by i-pairs ----
    // EC0[w] = (E[2w][j0], E[2w+1][j0]) ; EC1[w] = same for j1
    // Brute-force macro expansion: every array index is a literal constant so
    // SROA must promote EC0/EC1 to VGPRs (no unroll heuristic involved).
    unsigned int EC0[T_ / 2], EC1[T_ / 2];
#define INIT_W(w) { \
        float2 r0 = trans2[(2 * (w)) * (T_ / 2) + lane];      \
        float2 r1 = trans2[(2 * (w) + 1) * (T_ / 2) + lane];  \
        EC0[(w)] = pack2(__expf(r0.x), __expf(r1.x));         \
        EC1[(w)] = pack2(__expf(r0.y), __expf(r1.y)); }
#define INIT4(w)  INIT_W(w) INIT_W((w)+1) INIT_W((w)+2) INIT_W((w)+3)
#define INIT16(w) INIT4(w) INIT4((w)+4) INIT4((w)+8) INIT4((w)+12)
    INIT16(0) INIT16(16) INIT16(32) INIT16(48)
#undef INIT16
#undef INIT4
#undef INIT_W

    // ---- init: alpha_0 = emit_0 ----
    float2 e0 = featb2[lane];
    float m = fmaxf(e0.x, e0.y);
    #pragma unroll
    for (int off = 32; off >= 1; off >>= 1) m = fmaxf(m, __shfl_xor(m, off));
    float xc0 = __expf(e0.x - m);
    float xc1 = __expf(e0.y - m);
    float N = m;                          // running log-normalizer
    float S = xc0 + xc1;                  // exact sum of current x vector
    #pragma unroll
    for (int off = 32; off >= 1; off >>= 1) S += __shfl_xor(S, off);
    apk[0][lane] = pack2(xc0, xc1);       // same wave: in-order DS queue, no barrier

    // ---- emit/mask prefetch pipeline (depth 3) ----
    float2 fq  = featb2[1 * (T_ / 2) + lane];
    float2 fb1 = featb2[2 * (T_ / 2) + lane];
    float2 fb2 = featb2[3 * (T_ / 2) + lane];
    float exq0 = __expf(fq.x), exq1 = __expf(fq.y);
    int mkq = maskb[1], mkb1 = maskb[2], mkb2 = maskb[3];

    const float LOG128 = 4.8520302639196171f;
    int pr = 0;

    // ---- forward scan: barrier-free ----
    for (int t = 1; t < L_; ++t) {
        // prefetch emit/mask for t+3 (clamped) — latency hidden under dots
        const int tn = (t + 3 < L_) ? (t + 3) : (L_ - 1);
        float2 fn = featb2[tn * (T_ / 2) + lane];
        int    mn = maskb[tn];

        const float rcpC = 1.0f / (S * 128.0f);     // S from prev iter: overlaps ds_reads
        const float logC = __logf(S) + LOG128;

        float a00 = 0.f, a01 = 0.f, a02 = 0.f, a03 = 0.f;   // j0 chains
        float a10 = 0.f, a11 = 0.f, a12 = 0.f, a13 = 0.f;   // j1 chains
        const uint4* ap = (const uint4*)apk[pr];
#define DOTK(k) { \
        uint4 a4 = ap[(k)];                                  \
        a00 = dot2_acc(EC0[4 * (k) + 0], a4.x, a00);         \
        a10 = dot2_acc(EC1[4 * (k) + 0], a4.x, a10);         \
        a01 = dot2_acc(EC0[4 * (k) + 1], a4.y, a01);         \
        a11 = dot2_acc(EC1[4 * (k) + 1], a4.y, a11);         \
        a02 = dot2_acc(EC0[4 * (k) + 2], a4.z, a02);         \
        a12 = dot2_acc(EC1[4 * (k) + 2], a4.z, a12);         \
        a03 = dot2_acc(EC0[4 * (k) + 3], a4.w, a03);         \
        a13 = dot2_acc(EC1[4 * (k) + 3], a4.w, a13); }
#define DOT4(k) DOTK(k) DOTK((k)+1) DOTK((k)+2) DOTK((k)+3)
        DOT4(0) DOT4(4) DOT4(8) DOT4(12)
#undef DOT4
#undef DOTK
        const float ssum0 = (a00 + a01) + (a02 + a03);
        const float ssum1 = (a10 + a11) + (a12 + a13);

        const float x0 = ssum0 * exq0 * rcpC;
        const float x1 = ssum1 * exq1 * rcpC;
        if (mkq) { xc0 = x0; xc1 = x1; N += logC; }

        apk[pr ^ 1][lane] = pack2(xc0, xc1);

        // exact sum of committed vector (consumed next iter -> off critical path)
        float s = xc0 + xc1;
        #pragma unroll
        for (int off = 32; off >= 1; off >>= 1) s += __shfl_xor(s, off);
        S = s;

        // rotate prefetch pipeline
        exq0 = __expf(fb1.x); exq1 = __expf(fb1.y);
        mkq = mkb1;
        fb1 = fb2; mkb1 = mkb2;
        fb2 = fn;  mkb2 = mn;

        pr ^= 1;
    }

    // ---- norm = N + log(sum of final x) ----
    const float norm = N + __logf(S);

    // ---- gold path score ----
    float g = 0.f;
    for (int t = lane; t < L_; t += NTHR) {
        int tg = tagb[t];
        g += featb[t * T_ + tg] * (float)maskb[t];
        if (t + 1 < L_) {
            g += trans[tg * T_ + tagb[t + 1]] * (float)maskb[t + 1];
        }
    }
    #pragma unroll
    for (int off = 32; off >= 1; off >>= 1) g += __shfl_xor(g, off);

    if (lane == 0) out[b] = norm - g;
}

extern "C" void kernel_launch(void* const* d_in, const int* in_sizes, int n_in,
                              void* d_out, int out_size, void* d_ws, size_t ws_size,
                              hipStream_t stream) {
    const float* feats = (const float*)d_in[0];
    const float* trans = (const float*)d_in[1];
    const int*   tags  = (const int*)d_in[2];
    const int*   mask  = (const int*)d_in[3];
    float* out = (float*)d_out;

    crf_nll_kernel<<<B_, NTHR, 0, stream>>>(feats, trans, tags, mask, out);
}

// Round 7
// 257.897 us; speedup vs baseline: 1.3194x; 1.2456x over previous
//
#include <hip/hip_runtime.h>
#include <hip/hip_fp16.h>

#define B_ 64
#define L_ 512
#define T_ 128
#define NTHR 64     // ONE wave per batch: no barriers anywhere

typedef _Float16 h2v __attribute__((ext_vector_type(2)));
typedef __fp16   h2b __attribute__((ext_vector_type(2)));   // builtin return type

__device__ __forceinline__ float dot2_acc(unsigned int e, unsigned int a, float c) {
#if __has_builtin(__builtin_amdgcn_fdot2)
    h2v ev = __builtin_bit_cast(h2v, e);
    h2v av = __builtin_bit_cast(h2v, a);
    return __builtin_amdgcn_fdot2(ev, av, c, false);
#else
    __half2 eh = __builtin_bit_cast(__half2, e);
    __half2 ah = __builtin_bit_cast(__half2, a);
    float2 ef = __half22float2(eh), af = __half22float2(ah);
    return c + ef.x * af.x + ef.y * af.y;
#endif
}

__device__ __forceinline__ unsigned int pack2(float a, float b) {
#if __has_builtin(__builtin_amdgcn_cvt_pkrtz)
    h2b h = __builtin_amdgcn_cvt_pkrtz(a, b);
    return __builtin_bit_cast(unsigned int, h);
#else
    __half2 h = __floats2half2_rn(a, b);
    return __builtin_bit_cast(unsigned int, h);
#endif
}

// ---- pure-VALU wave-64 sum via DPP (no DS ops -> no lgkmcnt serialization) ----
// ctrl/row_mask must be compile-time constants -> template parameters.
template <int CTRL, int RMASK>
__device__ __forceinline__ float dpp_add(float v) {
    int t = __builtin_amdgcn_update_dpp(0, __builtin_bit_cast(int, v),
                                        CTRL, RMASK, 0xf, true);
    return v + __builtin_bit_cast(float, t);
}
__device__ __forceinline__ float wave_sum_bcast(float v) {
    v = dpp_add<0x111, 0xf>(v);   // row_shr:1
    v = dpp_add<0x112, 0xf>(v);   // row_shr:2
    v = dpp_add<0x114, 0xf>(v);   // row_shr:4
    v = dpp_add<0x118, 0xf>(v);   // row_shr:8  -> lane 15/31/47/63 hold row sums
    v = dpp_add<0x142, 0xa>(v);   // row_bcast:15 -> rows 1,3
    v = dpp_add<0x143, 0xc>(v);   // row_bcast:31 -> rows 2,3; lane 63 = total
    return __builtin_bit_cast(float,
        __builtin_amdgcn_readlane(__builtin_bit_cast(int, v), 63));
}

__global__ __launch_bounds__(NTHR, 1) void crf_nll_kernel(
        const float* __restrict__ feats,   // [B, L, T]
        const float* __restrict__ trans,   // [T, T]
        const int*   __restrict__ tags,    // [B, L]
        const int*   __restrict__ mask,    // [B, L]
        float*       __restrict__ out)     // [B]
{
    __shared__ __align__(16) unsigned int apk[2][T_ / 2];  // x as f16x2 over i-pairs

    const int lane = threadIdx.x;          // 0..63
    const int b    = blockIdx.x;

    const float*  featb  = feats + (size_t)b * L_ * T_;
    const float2* featb2 = (const float2*)featb;           // [L][64] pairs
    const float2* trans2 = (const float2*)trans;           // [T][64] pairs
    const int*    maskb  = mask + b * L_;
    const int*    tagb   = tags + b * L_;

    // ---- E columns (j0=2*lane, j1=2*lane+1) in registers, packed by i-pairs ----
    unsigned int EC0[T_ / 2], EC1[T_ / 2];
#define INIT_W(w) { \
        float2 r0 = trans2[(2 * (w)) * (T_ / 2) + lane];      \
        float2 r1 = trans2[(2 * (w) + 1) * (T_ / 2) + lane];  \
        EC0[(w)] = pack2(__expf(r0.x), __expf(r1.x));         \
        EC1[(w)] = pack2(__expf(r0.y), __expf(r1.y)); }
#define INIT4(w)  INIT_W(w) INIT_W((w)+1) INIT_W((w)+2) INIT_W((w)+3)
#define INIT16(w) INIT4(w) INIT4((w)+4) INIT4((w)+8) INIT4((w)+12)
    INIT16(0) INIT16(16) INIT16(32) INIT16(48)
#undef INIT16
#undef INIT4
#undef INIT_W

    // ---- init: alpha_0 = emit_0 ----
    float2 e0 = featb2[lane];
    float m = fmaxf(e0.x, e0.y);
    #pragma unroll
    for (int off = 32; off >= 1; off >>= 1) m = fmaxf(m, __shfl_xor(m, off));
    float xc0 = __expf(e0.x - m);
    float xc1 = __expf(e0.y - m);
    float N = m;                          // running log-normalizer
    float S = wave_sum_bcast(xc0 + xc1);  // exact sum of current x vector
    apk[0][lane] = pack2(xc0, xc1);       // same wave: in-order DS queue, no barrier

    // ---- emit/mask prefetch pipeline (depth 3) ----
    float2 fq  = featb2[1 * (T_ / 2) + lane];
    float2 fb1 = featb2[2 * (T_ / 2) + lane];
    float2 fb2 = featb2[3 * (T_ / 2) + lane];
    float exq0 = __expf(fq.x), exq1 = __expf(fq.y);
    int mkq = maskb[1], mkb1 = maskb[2], mkb2 = maskb[3];

    const float LOG128 = 4.8520302639196171f;
    int pr = 0;

    // ---- forward scan: barrier-free, DS queue holds only write+reads ----
    for (int t = 1; t < L_; ++t) {
        // prefetch emit/mask for t+3 (clamped) — latency hidden under dots
        const int tn = (t + 3 < L_) ? (t + 3) : (L_ - 1);
        float2 fn = featb2[tn * (T_ / 2) + lane];
        int    mn = maskb[tn];

        const float rcpC = 1.0f / (S * 128.0f);     // S from prev iter (DPP, ready early)
        const float logC = __logf(S) + LOG128;

        float a00 = 0.f, a01 = 0.f, a02 = 0.f, a03 = 0.f;   // j0 chains
        float a10 = 0.f, a11 = 0.f, a12 = 0.f, a13 = 0.f;   // j1 chains
        const uint4* ap = (const uint4*)apk[pr];
#define DOTK(k) { \
        uint4 a4 = ap[(k)];                                  \
        a00 = dot2_acc(EC0[4 * (k) + 0], a4.x, a00);         \
        a10 = dot2_acc(EC1[4 * (k) + 0], a4.x, a10);         \
        a01 = dot2_acc(EC0[4 * (k) + 1], a4.y, a01);         \
        a11 = dot2_acc(EC1[4 * (k) + 1], a4.y, a11);         \
        a02 = dot2_acc(EC0[4 * (k) + 2], a4.z, a02);         \
        a12 = dot2_acc(EC1[4 * (k) + 2], a4.z, a12);         \
        a03 = dot2_acc(EC0[4 * (k) + 3], a4.w, a03);         \
        a13 = dot2_acc(EC1[4 * (k) + 3], a4.w, a13); }
#define DOT4(k) DOTK(k) DOTK((k)+1) DOTK((k)+2) DOTK((k)+3)
        DOT4(0) DOT4(4) DOT4(8) DOT4(12)
#undef DOT4
#undef DOTK
        const float ssum0 = (a00 + a01) + (a02 + a03);
        const float ssum1 = (a10 + a11) + (a12 + a13);

        const float x0 = ssum0 * exq0 * rcpC;
        const float x1 = ssum1 * exq1 * rcpC;
        if (mkq) { xc0 = x0; xc1 = x1; N += logC; }

        apk[pr ^ 1][lane] = pack2(xc0, xc1);   // ds_write FIRST (DS queue clean)

        // exact sum of committed vector via DPP (pure VALU, off critical path)
        S = wave_sum_bcast(xc0 + xc1);

        // rotate prefetch pipeline
        exq0 = __expf(fb1.x); exq1 = __expf(fb1.y);
        mkq = mkb1;
        fb1 = fb2; mkb1 = mkb2;
        fb2 = fn;  mkb2 = mn;

        pr ^= 1;
    }

    // ---- norm = N + log(sum of final x) ----
    const float norm = N + __logf(S);

    // ---- gold path score ----
    float g = 0.f;
    for (int t = lane; t < L_; t += NTHR) {
        int tg = tagb[t];
        g += featb[t * T_ + tg] * (float)maskb[t];
        if (t + 1 < L_) {
            g += trans[tg * T_ + tagb[t + 1]] * (float)maskb[t + 1];
        }
    }
    #pragma unroll
    for (int off = 32; off >= 1; off >>= 1) g += __shfl_xor(g, off);

    if (lane == 0) out[b] = norm - g;
}

extern "C" void kernel_launch(void* const* d_in, const int* in_sizes, int n_in,
                              void* d_out, int out_size, void* d_ws, size_t ws_size,
                              hipStream_t stream) {
    const float* feats = (const float*)d_in[0];
    const float* trans = (const float*)d_in[1];
    const int*   tags  = (const int*)d_in[2];
    const int*   mask  = (const int*)d_in[3];
    float* out = (float*)d_out;

    crf_nll_kernel<<<B_, NTHR, 0, stream>>>(feats, trans, tags, mask, out);
}

// Round 8
// 236.957 us; speedup vs baseline: 1.4360x; 1.0884x over previous
//
#include <hip/hip_runtime.h>
#include <hip/hip_fp16.h>

#define B_ 64
#define L_ 512
#define T_ 128
#define NTHR 64     // ONE wave per batch: no barriers anywhere

typedef _Float16 h2v __attribute__((ext_vector_type(2)));
typedef __fp16   h2b __attribute__((ext_vector_type(2)));   // builtin return type

__device__ __forceinline__ float dot2_acc(unsigned int e, unsigned int a, float c) {
#if __has_builtin(__builtin_amdgcn_fdot2)
    h2v ev = __builtin_bit_cast(h2v, e);
    h2v av = __builtin_bit_cast(h2v, a);
    return __builtin_amdgcn_fdot2(ev, av, c, false);
#else
    __half2 eh = __builtin_bit_cast(__half2, e);
    __half2 ah = __builtin_bit_cast(__half2, a);
    float2 ef = __half22float2(eh), af = __half22float2(ah);
    return c + ef.x * af.x + ef.y * af.y;
#endif
}

__device__ __forceinline__ unsigned int pack2(float a, float b) {
#if __has_builtin(__builtin_amdgcn_cvt_pkrtz)
    h2b h = __builtin_amdgcn_cvt_pkrtz(a, b);
    return __builtin_bit_cast(unsigned int, h);
#else
    __half2 h = __floats2half2_rn(a, b);
    return __builtin_bit_cast(unsigned int, h);
#endif
}

// ---- pure-VALU wave-64 sum via DPP (no DS ops -> no lgkmcnt serialization) ----
template <int CTRL, int RMASK>
__device__ __forceinline__ float dpp_add(float v) {
    int t = __builtin_amdgcn_update_dpp(0, __builtin_bit_cast(int, v),
                                        CTRL, RMASK, 0xf, true);
    return v + __builtin_bit_cast(float, t);
}
__device__ __forceinline__ float wave_sum_bcast(float v) {
    v = dpp_add<0x111, 0xf>(v);   // row_shr:1
    v = dpp_add<0x112, 0xf>(v);   // row_shr:2
    v = dpp_add<0x114, 0xf>(v);   // row_shr:4
    v = dpp_add<0x118, 0xf>(v);   // row_shr:8  -> lane 15/31/47/63 hold row sums
    v = dpp_add<0x142, 0xa>(v);   // row_bcast:15 -> rows 1,3
    v = dpp_add<0x143, 0xc>(v);   // row_bcast:31 -> rows 2,3; lane 63 = total
    return __builtin_bit_cast(float,
        __builtin_amdgcn_readlane(__builtin_bit_cast(int, v), 63));
}

__global__ __launch_bounds__(NTHR, 1) void crf_nll_kernel(
        const float* __restrict__ feats,   // [B, L, T]
        const float* __restrict__ trans,   // [T, T]
        const int*   __restrict__ tags,    // [B, L]
        const int*   __restrict__ mask,    // [B, L]
        float*       __restrict__ out)     // [B]
{
    __shared__ __align__(16) unsigned int apk[2][T_ / 2];  // x as f16x2 over i-pairs

    const int lane = threadIdx.x;          // 0..63
    const int b    = blockIdx.x;

    const float*  featb  = feats + (size_t)b * L_ * T_;
    const float2* featb2 = (const float2*)featb;           // [L][64] pairs
    const float2* trans2 = (const float2*)trans;           // [T][64] pairs
    const int*    maskb  = mask + b * L_;
    const int*    tagb   = tags + b * L_;

    // ---- E columns (j0=2*lane, j1=2*lane+1) in registers, packed by i-pairs ----
    unsigned int EC0[T_ / 2], EC1[T_ / 2];
#define INIT_W(w) { \
        float2 r0 = trans2[(2 * (w)) * (T_ / 2) + lane];      \
        float2 r1 = trans2[(2 * (w) + 1) * (T_ / 2) + lane];  \
        EC0[(w)] = pack2(__expf(r0.x), __expf(r1.x));         \
        EC1[(w)] = pack2(__expf(r0.y), __expf(r1.y)); }
#define INIT4(w)  INIT_W(w) INIT_W((w)+1) INIT_W((w)+2) INIT_W((w)+3)
#define INIT16(w) INIT4(w) INIT4((w)+4) INIT4((w)+8) INIT4((w)+12)
    INIT16(0) INIT16(16) INIT16(32) INIT16(48)
#undef INIT16
#undef INIT4
#undef INIT_W

    // ---- init: alpha_0 = emit_0 ----
    float2 e0 = featb2[lane];
    float m = fmaxf(e0.x, e0.y);
    #pragma unroll
    for (int off = 32; off >= 1; off >>= 1) m = fmaxf(m, __shfl_xor(m, off));
    float xc0 = __expf(e0.x - m);
    float xc1 = __expf(e0.y - m);
    float N = m;                            // running log-normalizer
    float Sn = wave_sum_bcast(xc0 + xc1);   // exact sum of current x vector
    apk[0][lane] = pack2(xc0, xc1);         // same wave: in-order DS queue, no barrier

    // ---- 4-deep emit/mask slot pipeline (named regs, compile-time slots) ----
    float2 sf0 = featb2[1 * (T_ / 2) + lane];
    float2 sf1 = featb2[2 * (T_ / 2) + lane];
    float2 sf2 = featb2[3 * (T_ / 2) + lane];
    float2 sf3 = featb2[4 * (T_ / 2) + lane];
    int sm0 = maskb[1], sm1 = maskb[2], sm2 = maskb[3], sm3 = maskb[4];

    const float LOG128 = 4.8520302639196171f;
    int pr = 0;
    int t  = 1;

#define DOTK(k) { \
        uint4 a4 = ap[(k)];                                  \
        a00 = dot2_acc(EC0[4 * (k) + 0], a4.x, a00);         \
        a10 = dot2_acc(EC1[4 * (k) + 0], a4.x, a10);         \
        a01 = dot2_acc(EC0[4 * (k) + 1], a4.y, a01);         \
        a11 = dot2_acc(EC1[4 * (k) + 1], a4.y, a11);         \
        a02 = dot2_acc(EC0[4 * (k) + 2], a4.z, a02);         \
        a12 = dot2_acc(EC1[4 * (k) + 2], a4.z, a12);         \
        a03 = dot2_acc(EC0[4 * (k) + 3], a4.w, a03);         \
        a13 = dot2_acc(EC1[4 * (k) + 3], a4.w, a13); }
#define DOT4(k) DOTK(k) DOTK((k)+1) DOTK((k)+2) DOTK((k)+3)

#define STEP(S) { \
        /* consume slot S (loaded 4 iterations ago -> vmcnt slack ~4 bodies) */ \
        const float2 fcur = sf##S;                           \
        const int    mcur = sm##S;                           \
        /* re-issue slot S for t+4 (clamped) */              \
        const int tn = (t + 4 < L_) ? (t + 4) : (L_ - 1);    \
        sf##S = featb2[tn * (T_ / 2) + lane];                \
        sm##S = maskb[tn];                                   \
        const float exq0 = __expf(fcur.x);                   \
        const float exq1 = __expf(fcur.y);                   \
        const float rcpC = 1.0f / (Sn * 128.0f);             \
        const float logC = __logf(Sn) + LOG128;              \
        float a00 = 0.f, a01 = 0.f, a02 = 0.f, a03 = 0.f;    \
        float a10 = 0.f, a11 = 0.f, a12 = 0.f, a13 = 0.f;    \
        const uint4* ap = (const uint4*)apk[pr];             \
        DOT4(0) DOT4(4) DOT4(8) DOT4(12)                     \
        const float ssum0 = (a00 + a01) + (a02 + a03);       \
        const float ssum1 = (a10 + a11) + (a12 + a13);       \
        const float x0 = ssum0 * exq0 * rcpC;                \
        const float x1 = ssum1 * exq1 * rcpC;                \
        if (mcur) { xc0 = x0; xc1 = x1; N += logC; }         \
        apk[pr ^ 1][lane] = pack2(xc0, xc1);                 \
        Sn = wave_sum_bcast(xc0 + xc1);                      \
        pr ^= 1; ++t;                                        \
    }

    // 511 steps = 127 quads + 3
    for (int q = 0; q < 127; ++q) { STEP(0) STEP(1) STEP(2) STEP(3) }
    STEP(0) STEP(1) STEP(2)

#undef STEP
#undef DOT4
#undef DOTK

    // ---- norm = N + log(sum of final x) ----
    const float norm = N + __logf(Sn);

    // ---- gold path score ----
    float g = 0.f;
    for (int tt = lane; tt < L_; tt += NTHR) {
        int tg = tagb[tt];
        g += featb[tt * T_ + tg] * (float)maskb[tt];
        if (tt + 1 < L_) {
            g += trans[tg * T_ + tagb[tt + 1]] * (float)maskb[tt + 1];
        }
    }
    #pragma unroll
    for (int off = 32; off >= 1; off >>= 1) g += __shfl_xor(g, off);

    if (lane == 0) out[b] = norm - g;
}

extern "C" void kernel_launch(void* const* d_in, const int* in_sizes, int n_in,
                              void* d_out, int out_size, void* d_ws, size_t ws_size,
                              hipStream_t stream) {
    const float* feats = (const float*)d_in[0];
    const float* trans = (const float*)d_in[1];
    const int*   tags  = (const int*)d_in[2];
    const int*   mask  = (const int*)d_in[3];
    float* out = (float*)d_out;

    crf_nll_kernel<<<B_, NTHR, 0, stream>>>(feats, trans, tags, mask, out);
}

// Round 9
// 236.200 us; speedup vs baseline: 1.4406x; 1.0032x over previous
//
#include <hip/hip_runtime.h>
#include <hip/hip_fp16.h>

#define B_ 64
#define L_ 512
#define T_ 128
#define NTHR 64     // ONE wave per batch: no barriers anywhere

typedef _Float16 h2v __attribute__((ext_vector_type(2)));
typedef __fp16   h2b __attribute__((ext_vector_type(2)));   // builtin return type
typedef unsigned int u32x4 __attribute__((ext_vector_type(4)));

__device__ __forceinline__ float dot2_acc(unsigned int e, unsigned int a, float c) {
#if __has_builtin(__builtin_amdgcn_fdot2)
    h2v ev = __builtin_bit_cast(h2v, e);
    h2v av = __builtin_bit_cast(h2v, a);
    return __builtin_amdgcn_fdot2(ev, av, c, false);
#else
    __half2 eh = __builtin_bit_cast(__half2, e);
    __half2 ah = __builtin_bit_cast(__half2, a);
    float2 ef = __half22float2(eh), af = __half22float2(ah);
    return c + ef.x * af.x + ef.y * af.y;
#endif
}

__device__ __forceinline__ unsigned int pack2(float a, float b) {
#if __has_builtin(__builtin_amdgcn_cvt_pkrtz)
    h2b h = __builtin_amdgcn_cvt_pkrtz(a, b);
    return __builtin_bit_cast(unsigned int, h);
#else
    __half2 h = __floats2half2_rn(a, b);
    return __builtin_bit_cast(unsigned int, h);
#endif
}

// ---- pure-VALU wave-64 sum via DPP (no DS ops -> no lgkmcnt serialization) ----
template <int CTRL, int RMASK>
__device__ __forceinline__ float dpp_add(float v) {
    int t = __builtin_amdgcn_update_dpp(0, __builtin_bit_cast(int, v),
                                        CTRL, RMASK, 0xf, true);
    return v + __builtin_bit_cast(float, t);
}
__device__ __forceinline__ float wave_sum_bcast(float v) {
    v = dpp_add<0x111, 0xf>(v);   // row_shr:1
    v = dpp_add<0x112, 0xf>(v);   // row_shr:2
    v = dpp_add<0x114, 0xf>(v);   // row_shr:4
    v = dpp_add<0x118, 0xf>(v);   // row_shr:8  -> lane 15/31/47/63 hold row sums
    v = dpp_add<0x142, 0xa>(v);   // row_bcast:15 -> rows 1,3
    v = dpp_add<0x143, 0xc>(v);   // row_bcast:31 -> rows 2,3; lane 63 = total
    return __builtin_bit_cast(float,
        __builtin_amdgcn_readlane(__builtin_bit_cast(int, v), 63));
}

__global__ __launch_bounds__(NTHR, 1) void crf_nll_kernel(
        const float* __restrict__ feats,   // [B, L, T]
        const float* __restrict__ trans,   // [T, T]
        const int*   __restrict__ tags,    // [B, L]
        const int*   __restrict__ mask,    // [B, L]
        float*       __restrict__ out)     // [B]
{
    __shared__ __align__(16) unsigned int apk[2][T_ / 2];  // x as f16x2 over i-pairs

    const int lane = threadIdx.x;          // 0..63
    const int b    = blockIdx.x;

    const float*  featb  = feats + (size_t)b * L_ * T_;
    const float2* featb2 = (const float2*)featb;           // [L][64] pairs
    const float2* trans2 = (const float2*)trans;           // [T][64] pairs
    const int*    maskb  = mask + b * L_;
    const int*    tagb   = tags + b * L_;

    // ---- E columns (j0=2*lane, j1=2*lane+1) as 32 NAMED ext-vector SSA values ----
    // ec0_k.{x,y,z,w} = EC0[4k..4k+3], EC0[w] = (E[2w][j0], E[2w+1][j0]); same for j1.
    // Named first-class vector values cannot be demoted to scratch (vs arrays).
    u32x4 ec0_0, ec0_1, ec0_2, ec0_3, ec0_4, ec0_5, ec0_6, ec0_7,
          ec0_8, ec0_9, ec0_10, ec0_11, ec0_12, ec0_13, ec0_14, ec0_15;
    u32x4 ec1_0, ec1_1, ec1_2, ec1_3, ec1_4, ec1_5, ec1_6, ec1_7,
          ec1_8, ec1_9, ec1_10, ec1_11, ec1_12, ec1_13, ec1_14, ec1_15;

#define INIT_Q(k) { \
        float2 r0 = trans2[(8 * (k) + 0) * (T_ / 2) + lane]; \
        float2 r1 = trans2[(8 * (k) + 1) * (T_ / 2) + lane]; \
        float2 r2 = trans2[(8 * (k) + 2) * (T_ / 2) + lane]; \
        float2 r3 = trans2[(8 * (k) + 3) * (T_ / 2) + lane]; \
        float2 r4 = trans2[(8 * (k) + 4) * (T_ / 2) + lane]; \
        float2 r5 = trans2[(8 * (k) + 5) * (T_ / 2) + lane]; \
        float2 r6 = trans2[(8 * (k) + 6) * (T_ / 2) + lane]; \
        float2 r7 = trans2[(8 * (k) + 7) * (T_ / 2) + lane]; \
        ec0_##k.x = pack2(__expf(r0.x), __expf(r1.x));       \
        ec0_##k.y = pack2(__expf(r2.x), __expf(r3.x));       \
        ec0_##k.z = pack2(__expf(r4.x), __expf(r5.x));       \
        ec0_##k.w = pack2(__expf(r6.x), __expf(r7.x));       \
        ec1_##k.x = pack2(__expf(r0.y), __expf(r1.y));       \
        ec1_##k.y = pack2(__expf(r2.y), __expf(r3.y));       \
        ec1_##k.z = pack2(__expf(r4.y), __expf(r5.y));       \
        ec1_##k.w = pack2(__expf(r6.y), __expf(r7.y)); }
    INIT_Q(0)  INIT_Q(1)  INIT_Q(2)  INIT_Q(3)
    INIT_Q(4)  INIT_Q(5)  INIT_Q(6)  INIT_Q(7)
    INIT_Q(8)  INIT_Q(9)  INIT_Q(10) INIT_Q(11)
    INIT_Q(12) INIT_Q(13) INIT_Q(14) INIT_Q(15)
#undef INIT_Q

    // ---- init: alpha_0 = emit_0 ----
    float2 e0 = featb2[lane];
    float m = fmaxf(e0.x, e0.y);
    #pragma unroll
    for (int off = 32; off >= 1; off >>= 1) m = fmaxf(m, __shfl_xor(m, off));
    float xc0 = __expf(e0.x - m);
    float xc1 = __expf(e0.y - m);
    float N = m;                            // running log-normalizer
    float Sn = wave_sum_bcast(xc0 + xc1);   // exact sum of current x vector
    apk[0][lane] = pack2(xc0, xc1);         // same wave: in-order DS queue, no barrier

    // ---- 4-deep emit/mask slot pipeline (named regs, compile-time slots) ----
    float2 sf0 = featb2[1 * (T_ / 2) + lane];
    float2 sf1 = featb2[2 * (T_ / 2) + lane];
    float2 sf2 = featb2[3 * (T_ / 2) + lane];
    float2 sf3 = featb2[4 * (T_ / 2) + lane];
    int sm0 = maskb[1], sm1 = maskb[2], sm2 = maskb[3], sm3 = maskb[4];

    const float LOG128 = 4.8520302639196171f;
    int pr = 0;
    int t  = 1;

#define DOTK(k) { \
        u32x4 a4 = ap[(k)];                              \
        a00 = dot2_acc(ec0_##k.x, a4.x, a00);            \
        a10 = dot2_acc(ec1_##k.x, a4.x, a10);            \
        a01 = dot2_acc(ec0_##k.y, a4.y, a01);            \
        a11 = dot2_acc(ec1_##k.y, a4.y, a11);            \
        a02 = dot2_acc(ec0_##k.z, a4.z, a02);            \
        a12 = dot2_acc(ec1_##k.z, a4.z, a12);            \
        a03 = dot2_acc(ec0_##k.w, a4.w, a03);            \
        a13 = dot2_acc(ec1_##k.w, a4.w, a13); }

#define STEP(S) { \
        /* consume slot S (loaded 4 iterations ago -> vmcnt slack ~4 bodies) */ \
        const float2 fcur = sf##S;                           \
        const int    mcur = sm##S;                           \
        /* re-issue slot S for t+4 (clamped) */              \
        const int tn = (t + 4 < L_) ? (t + 4) : (L_ - 1);    \
        sf##S = featb2[tn * (T_ / 2) + lane];                \
        sm##S = maskb[tn];                                   \
        const float exq0 = __expf(fcur.x);                   \
        const float exq1 = __expf(fcur.y);                   \
        const float rcpC = 1.0f / (Sn * 128.0f);             \
        const float logC = __logf(Sn) + LOG128;              \
        float a00 = 0.f, a01 = 0.f, a02 = 0.f, a03 = 0.f;    \
        float a10 = 0.f, a11 = 0.f, a12 = 0.f, a13 = 0.f;    \
        const u32x4* ap = (const u32x4*)apk[pr];             \
        DOTK(0)  DOTK(1)  DOTK(2)  DOTK(3)                   \
        DOTK(4)  DOTK(5)  DOTK(6)  DOTK(7)                   \
        DOTK(8)  DOTK(9)  DOTK(10) DOTK(11)                  \
        DOTK(12) DOTK(13) DOTK(14) DOTK(15)                  \
        const float ssum0 = (a00 + a01) + (a02 + a03);       \
        const float ssum1 = (a10 + a11) + (a12 + a13);       \
        const float x0 = ssum0 * exq0 * rcpC;                \
        const float x1 = ssum1 * exq1 * rcpC;                \
        if (mcur) { xc0 = x0; xc1 = x1; N += logC; }         \
        apk[pr ^ 1][lane] = pack2(xc0, xc1);                 \
        Sn = wave_sum_bcast(xc0 + xc1);                      \
        pr ^= 1; ++t;                                        \
    }

    // 511 steps = 127 quads + 3
    for (int q = 0; q < 127; ++q) { STEP(0) STEP(1) STEP(2) STEP(3) }
    STEP(0) STEP(1) STEP(2)

#undef STEP
#undef DOTK

    // ---- norm = N + log(sum of final x) ----
    const float norm = N + __logf(Sn);

    // ---- gold path score ----
    float g = 0.f;
    for (int tt = lane; tt < L_; tt += NTHR) {
        int tg = tagb[tt];
        g += featb[tt * T_ + tg] * (float)maskb[tt];
        if (tt + 1 < L_) {
            g += trans[tg * T_ + tagb[tt + 1]] * (float)maskb[tt + 1];
        }
    }
    #pragma unroll
    for (int off = 32; off >= 1; off >>= 1) g += __shfl_xor(g, off);

    if (lane == 0) out[b] = norm - g;
}

extern "C" void kernel_launch(void* const* d_in, const int* in_sizes, int n_in,
                              void* d_out, int out_size, void* d_ws, size_t ws_size,
                              hipStream_t stream) {
    const float* feats = (const float*)d_in[0];
    const float* trans = (const float*)d_in[1];
    const int*   tags  = (const int*)d_in[2];
    const int*   mask  = (const int*)d_in[3];
    float* out = (float*)d_out;

    crf_nll_kernel<<<B_, NTHR, 0, stream>>>(feats, trans, tags, mask, out);
}

// Round 11
// 223.112 us; speedup vs baseline: 1.5251x; 1.0587x over previous
//
#include <hip/hip_runtime.h>
#include <hip/hip_fp16.h>

#define B_ 64
#define L_ 512
#define T_ 128
#define NTHR 128    // 2 waves; one tag j per thread; raw s_barrier (no vmcnt drain)

typedef _Float16 h2v __attribute__((ext_vector_type(2)));
typedef __fp16   h2b __attribute__((ext_vector_type(2)));
typedef unsigned int u32x4 __attribute__((ext_vector_type(4)));

__device__ __forceinline__ float dot2_acc(unsigned int e, unsigned int a, float c) {
#if __has_builtin(__builtin_amdgcn_fdot2)
    h2v ev = __builtin_bit_cast(h2v, e);
    h2v av = __builtin_bit_cast(h2v, a);
    return __builtin_amdgcn_fdot2(ev, av, c, false);
#else
    __half2 eh = __builtin_bit_cast(__half2, e);
    __half2 ah = __builtin_bit_cast(__half2, a);
    float2 ef = __half22float2(eh), af = __half22float2(ah);
    return c + ef.x * af.x + ef.y * af.y;
#endif
}

__device__ __forceinline__ unsigned int pack2(float a, float b) {
#if __has_builtin(__builtin_amdgcn_cvt_pkrtz)
    h2b h = __builtin_amdgcn_cvt_pkrtz(a, b);
    return __builtin_bit_cast(unsigned int, h);
#else
    __half2 h = __floats2half2_rn(a, b);
    return __builtin_bit_cast(unsigned int, h);
#endif
}

// ---- pure-VALU wave-64 sum via DPP; total lands in lane 63 ----
template <int CTRL, int RMASK>
__device__ __forceinline__ float dpp_add(float v) {
    int t = __builtin_amdgcn_update_dpp(0, __builtin_bit_cast(int, v),
                                        CTRL, RMASK, 0xf, true);
    return v + __builtin_bit_cast(float, t);
}
__device__ __forceinline__ float wave_sum_lane63(float v) {
    v = dpp_add<0x111, 0xf>(v);   // row_shr:1
    v = dpp_add<0x112, 0xf>(v);   // row_shr:2
    v = dpp_add<0x114, 0xf>(v);   // row_shr:4
    v = dpp_add<0x118, 0xf>(v);   // row_shr:8  -> lanes 15/31/47/63 = row sums
    v = dpp_add<0x142, 0xa>(v);   // row_bcast:15 -> rows 1,3
    v = dpp_add<0x143, 0xc>(v);   // row_bcast:31 -> lane 63 = wave total
    return v;
}

__global__ __launch_bounds__(NTHR, 1) void crf_nll_kernel(
        const float* __restrict__ feats,   // [B, L, T]
        const float* __restrict__ trans,   // [T, T]
        const int*   __restrict__ tags,    // [B, L]
        const int*   __restrict__ mask,    // [B, L]
        float*       __restrict__ out)     // [B]
{
    __shared__ __align__(16) __half xbuf[2][T_];   // x vector as f16, double-buffered
    __shared__ __align__(16) float Shalf[2][2];    // per-wave half sums, double-buffered
    __shared__ __align__(16) float redx[4];

    const int tid  = threadIdx.x;
    const int lane = tid & 63;
    const int w    = tid >> 6;
    const int j    = tid;                 // this thread's tag column
    const int b    = blockIdx.x;

    const float* featb = feats + (size_t)b * L_ * T_;
    const int*   maskb = mask + b * L_;
    const int*   tagb  = tags + b * L_;

    // ---- E column j in registers: 16 named u32x4 = 64 VGPR (f16x2 over i-pairs) ----
    // ec_k component c = i-pair p=4k+c = (E[2p][j], E[2p+1][j])
    u32x4 ec_0, ec_1, ec_2, ec_3, ec_4, ec_5, ec_6, ec_7,
          ec_8, ec_9, ec_10, ec_11, ec_12, ec_13, ec_14, ec_15;
#define INIT_Q(k) { \
        float r0 = trans[(8 * (k) + 0) * T_ + j]; \
        float r1 = trans[(8 * (k) + 1) * T_ + j]; \
        float r2 = trans[(8 * (k) + 2) * T_ + j]; \
        float r3 = trans[(8 * (k) + 3) * T_ + j]; \
        float r4 = trans[(8 * (k) + 4) * T_ + j]; \
        float r5 = trans[(8 * (k) + 5) * T_ + j]; \
        float r6 = trans[(8 * (k) + 6) * T_ + j]; \
        float r7 = trans[(8 * (k) + 7) * T_ + j]; \
        ec_##k.x = pack2(__expf(r0), __expf(r1)); \
        ec_##k.y = pack2(__expf(r2), __expf(r3)); \
        ec_##k.z = pack2(__expf(r4), __expf(r5)); \
        ec_##k.w = pack2(__expf(r6), __expf(r7)); }
    INIT_Q(0)  INIT_Q(1)  INIT_Q(2)  INIT_Q(3)
    INIT_Q(4)  INIT_Q(5)  INIT_Q(6)  INIT_Q(7)
    INIT_Q(8)  INIT_Q(9)  INIT_Q(10) INIT_Q(11)
    INIT_Q(12) INIT_Q(13) INIT_Q(14) INIT_Q(15)
#undef INIT_Q

    // ---- init: alpha_0 = emit_0 (cross-wave max via LDS, pipeline not started yet) ----
    float e0 = featb[j];
    {
        float v = e0;
        #pragma unroll
        for (int off = 32; off >= 1; off >>= 1) v = fmaxf(v, __shfl_xor(v, off));
        if (lane == 0) redx[w] = v;
    }
    __syncthreads();
    const float m0 = fmaxf(redx[0], redx[1]);
    float xc = __expf(e0 - m0);
    float N  = m0;                         // running log-normalizer (uniform)
    xbuf[0][j] = __float2half(xc);
    {
        float s = wave_sum_lane63(xc);
        if (lane == 63) Shalf[0][w] = s;
    }
    __syncthreads();                       // publish xbuf[0], Shalf[0]

    // ---- 4-deep emit/mask slot pipeline (vector loads, vmcnt-queued) ----
    float sf0, sf1, sf2, sf3;
    int   sm0, sm1, sm2, sm3;
#define PRELOAD(S, tt) { \
        int tq = ((tt) < L_) ? (tt) : (L_ - 1);          \
        sf##S = featb[tq * T_ + j];                      \
        int tqv = tq; asm("" : "+v"(tqv));               \
        sm##S = maskb[tqv]; }
    PRELOAD(0, 1) PRELOAD(1, 2) PRELOAD(2, 3) PRELOAD(3, 4)
#undef PRELOAD

    const float LOG128 = 4.8520302639196171f;
    int pr = 0;
    int t  = 1;

#define DOTQ(k) { \
        u32x4 a4 = ap[(k)];                       \
        a0 = dot2_acc(ec_##k.x, a4.x, a0);        \
        a1 = dot2_acc(ec_##k.y, a4.y, a1);        \
        a2 = dot2_acc(ec_##k.z, a4.z, a2);        \
        a3 = dot2_acc(ec_##k.w, a4.w, a3); }

#define STEP(S) { \
        const float fcur = sf##S;                             \
        const int   mcur = sm##S;                             \
        const int tn = (t + 4 < L_) ? (t + 4) : (L_ - 1);     \
        sf##S = featb[tn * T_ + j];                           \
        int tnv = tn; asm("" : "+v"(tnv));                    \
        sm##S = maskb[tnv];                                   \
        /* stale half-sums first into lgkm queue */           \
        const float2 sh = *(const float2*)&Shalf[pr][0];      \
        const float exq = __expf(fcur);                       \
        float a0 = 0.f, a1 = 0.f, a2 = 0.f, a3 = 0.f;         \
        const u32x4* ap = (const u32x4*)xbuf[pr];             \
        DOTQ(0)  DOTQ(1)  DOTQ(2)  DOTQ(3)                    \
        DOTQ(4)  DOTQ(5)  DOTQ(6)  DOTQ(7)                    \
        DOTQ(8)  DOTQ(9)  DOTQ(10) DOTQ(11)                   \
        DOTQ(12) DOTQ(13) DOTQ(14) DOTQ(15)                   \
        const float ssum = (a0 + a1) + (a2 + a3);             \
        const float Stot = sh.x + sh.y;                       \
        const float rcpC = 1.0f / (Stot * 128.0f);            \
        const float logC = __logf(Stot) + LOG128;             \
        const float x = ssum * exq * rcpC;                    \
        if (mcur) { xc = x; N += logC; }                      \
        xbuf[pr ^ 1][j] = __float2half(xc);                   \
        float sl = wave_sum_lane63(xc);                       \
        if (lane == 63) Shalf[pr ^ 1][w] = sl;                \
        asm volatile("s_waitcnt lgkmcnt(0)" ::: "memory");    \
        __builtin_amdgcn_s_barrier();                         \
        __builtin_amdgcn_sched_barrier(0);                    \
        pr ^= 1; ++t;                                         \
    }

    // 511 steps = 127 quads + 3
    for (int q = 0; q < 127; ++q) { STEP(0) STEP(1) STEP(2) STEP(3) }
    STEP(0) STEP(1) STEP(2)

#undef STEP
#undef DOTQ

    // ---- norm = N + log(sum of final x) (final barrier already executed) ----
    const float2 shF = *(const float2*)&Shalf[pr][0];
    const float norm = N + __logf(shF.x + shF.y);

    // ---- gold path score (128 threads) ----
    float g = 0.f;
    for (int tt = tid; tt < L_; tt += NTHR) {
        int tg = tagb[tt];
        g += featb[tt * T_ + tg] * (float)maskb[tt];
        if (tt + 1 < L_) {
            g += trans[tg * T_ + tagb[tt + 1]] * (float)maskb[tt + 1];
        }
    }
    #pragma unroll
    for (int off = 32; off >= 1; off >>= 1) g += __shfl_xor(g, off);
    if (lane == 0) redx[2 + w] = g;
    __syncthreads();

    if (tid == 0) out[b] = norm - (redx[2] + redx[3]);
}

extern "C" void kernel_launch(void* const* d_in, const int* in_sizes, int n_in,
                              void* d_out, int out_size, void* d_ws, size_t ws_size,
                              hipStream_t stream) {
    const float* feats = (const float*)d_in[0];
    const float* trans = (const float*)d_in[1];
    const int*   tags  = (const int*)d_in[2];
    const int*   mask  = (const int*)d_in[3];
    float* out = (float*)d_out;

    crf_nll_kernel<<<B_, NTHR, 0, stream>>>(feats, trans, tags, mask, out);
}